// Round 14
// baseline (1573.151 us; speedup 1.0000x reference)
//
#include <hip/hip_runtime.h>
#include <hip/hip_bf16.h>
#include <math.h>

typedef __attribute__((ext_vector_type(4))) float f32x4;
typedef __attribute__((ext_vector_type(8))) short bf16x8;

constexpr int kB = 128, kT = 20, kH = 1024, kE = 512, kP = 36, kRaw = 2048, kV = 12000;
constexpr int kSlab1 = kB * 5120;
constexpr int kSlab2 = kB * 4096;

__device__ __forceinline__ float sigf(float x) { return 1.0f / (1.0f + expf(-x)); }

#define AS1C const __attribute__((address_space(1))) void*
#define AS3P __attribute__((address_space(3))) void*

// ---------------------------------------------------------------- merged prep
constexpr int NZ1 = 2 * kB * kH / 4;        // float4 zeros over c1,c2
constexpr int NZ2 = 2 * kB * kH * 2 / 16;   // uint4 zeros over h1b,h2b
constexpr int NCV = kB * kP * kRaw / 4;     // images -> bf16 (4 per thread)
constexpr int NPV = 64 * 1024 * 2 / 16;     // WTv zero (uint4)
constexpr int NPF = 32 * 1024 * 2 / 16;     // WTfc pad zero (uint4)
constexpr int NPB = 5120;                   // pack biases
constexpr int NGE = kB * kT * kE;           // gather embeddings

__global__ __launch_bounds__(256) void prep_small(
    float* c1z, uint4* h1z, const float* images, __hip_bfloat16* imagesb,
    uint4* wtv, uint4* wtfc_pad,
    const float* b_ih1, const float* b_hh1, const float* bx, const float* bh,
    const float* b_ih2, const float* b_hh2, float* bias_g1, float* bias_g2,
    const int* caps, const float* emb, __hip_bfloat16* wembb) {
  long idx = (long)blockIdx.x * 256 + threadIdx.x;
  if (idx < NZ1) { reinterpret_cast<float4*>(c1z)[idx] = make_float4(0, 0, 0, 0); return; }
  idx -= NZ1;
  if (idx < NZ2) { h1z[idx] = make_uint4(0, 0, 0, 0); return; }
  idx -= NZ2;
  if (idx < NCV) {
    float4 v = reinterpret_cast<const float4*>(images)[idx];
    __hip_bfloat16* d = imagesb + idx * 4;
    d[0] = __float2bfloat16(v.x); d[1] = __float2bfloat16(v.y);
    d[2] = __float2bfloat16(v.z); d[3] = __float2bfloat16(v.w);
    return;
  }
  idx -= NCV;
  if (idx < NPV) { wtv[idx] = make_uint4(0, 0, 0, 0); return; }
  idx -= NPV;
  if (idx < NPF) { wtfc_pad[idx] = make_uint4(0, 0, 0, 0); return; }
  idx -= NPF;
  if (idx < NPB) {
    int i = (int)idx;
    if (i < 4096) {
      bias_g1[i] = b_ih1[i] + b_hh1[i];
      bias_g2[i] = b_ih2[i] + b_hh2[i];
    } else {
      bias_g1[i] = bx[i - 4096] + bh[i - 4096];
    }
    return;
  }
  idx -= NPB;
  if (idx < NGE) {
    int e = (int)(idx % kE);
    int bt = (int)(idx / kE);
    int t = bt % kT;
    int b = bt / kT;
    int tok = caps[b * (kT + 1) + t];
    wembb[idx] = __float2bfloat16(emb[(size_t)tok * kE + e]);
  }
}

// ------------------------------------------------ merged weight transposes
struct TJob {
  const float* src; __hip_bfloat16* dst;
  int ld_src, K, N, lddst, koff, noff, blk_off, nbx;
};
struct TAll { TJob job[12]; int njobs; int total_blocks; };

__global__ __launch_bounds__(256) void transpose_all(TAll ta) {
  __shared__ float t[32][33];
  int bid = blockIdx.x;
  int ji = 0;
  while (ji + 1 < ta.njobs && bid >= ta.job[ji + 1].blk_off) ++ji;
  const TJob& J = ta.job[ji];
  int lbid = bid - J.blk_off;
  int n0 = (lbid % J.nbx) * 32, k0 = (lbid / J.nbx) * 32;
  int tx = threadIdx.x & 31, ty = threadIdx.x >> 5;  // 32 x 8
  #pragma unroll
  for (int i = 0; i < 32; i += 8) {
    int k = k0 + ty + i, n = n0 + tx;
    t[ty + i][tx] = (k < J.K && n < J.N) ? J.src[(size_t)k * J.ld_src + n] : 0.0f;
  }
  __syncthreads();
  #pragma unroll
  for (int i = 0; i < 32; i += 8) {
    int n = n0 + ty + i, k = k0 + tx;
    if (n < J.N && k < J.K)
      J.dst[(size_t)(n + J.noff) * J.lddst + k + J.koff] = __float2bfloat16(t[tx][ty + i]);
  }
}

// ------------------------------------------------------- 64x64 bf16 MFMA GEMM
// BK=64 (32 KB LDS -> up to 5 blocks/CU for latency hiding on skinny GEMMs),
// 2-buffer counted-vmcnt pipeline. Split-K via gridDim.z (K/z mult of 64;
// all seg boundaries multiples of 64).
struct SegB { const __hip_bfloat16* A; int lda; int kstart; int kend; };
struct GemmBArgs {
  SegB seg[4]; int nseg;
  const __hip_bfloat16* WT; int ldk;
  const float* bias;
  float* C; __hip_bfloat16* C16; int ldc; int N; int Ktot; int act; int zstride;
};

__global__ __launch_bounds__(256) void gemm_bf16(GemmBArgs ga) {
  __shared__ char lds[32768];  // 2 bufs x (A 8K | B 8K)
  const int bm = blockIdx.y * 64;
  const int bn = blockIdx.x * 64;
  const int tid = threadIdx.x;
  const int lane = tid & 63;
  const int w = tid >> 6;
  const int wr = w >> 1, wc = w & 1;

  // staging: 2 rounds per 8 KB matrix tile (4 KB per round); 128 B rows (BK=64)
  int rowS[2], scbS[2], dstS[2];
  #pragma unroll
  for (int j = 0; j < 2; ++j) {
    int off = ((j * 4 + w) * 64 + lane) * 16;   // linear byte in 8 KB tile
    int row = off >> 7, colb = off & 127;
    rowS[j] = row;
    scbS[j] = colb ^ ((row & 7) << 4);
    dstS[j] = off;
  }

  f32x4 acc[2][2] = {};
  const int nz = gridDim.z;
  const int nit = (ga.Ktot >> 6) / nz;
  const int it0 = blockIdx.z * nit;
  float* C = ga.C + (size_t)blockIdx.z * ga.zstride;

  auto stage = [&](int it, int buf) {
    const int k0 = it << 6;
    int si = 0;
    while (k0 >= ga.seg[si].kend) ++si;
    const __hip_bfloat16* Aseg = ga.seg[si].A;
    const int lda = ga.seg[si].lda;
    const int ks = k0 - ga.seg[si].kstart;
    char* baseA = lds + buf * 16384;
    char* baseB = baseA + 8192;
    #pragma unroll
    for (int j = 0; j < 2; ++j) {
      const __hip_bfloat16* sA = Aseg + (size_t)(bm + rowS[j]) * lda + ks + (scbS[j] >> 1);
      __builtin_amdgcn_global_load_lds((AS1C)sA, (AS3P)(baseA + dstS[j]), 16, 0, 0);
      const __hip_bfloat16* sB = ga.WT + (size_t)(bn + rowS[j]) * ga.ldk + k0 + (scbS[j] >> 1);
      __builtin_amdgcn_global_load_lds((AS1C)sB, (AS3P)(baseB + dstS[j]), 16, 0, 0);
    }
  };

  auto compute = [&](int buf) {
    const char* baseA = lds + buf * 16384;
    const char* baseB = baseA + 8192;
    #pragma unroll
    for (int kk = 0; kk < 2; ++kk) {
      bf16x8 a[2], b[2];
      int cb = kk * 64 + (lane >> 4) * 16;
      #pragma unroll
      for (int f = 0; f < 2; ++f) {
        int row = wr * 32 + f * 16 + (lane & 15);
        a[f] = *(const bf16x8*)(baseA + row * 128 + (cb ^ ((row & 7) << 4)));
        int nl = wc * 32 + f * 16 + (lane & 15);
        b[f] = *(const bf16x8*)(baseB + nl * 128 + (cb ^ ((nl & 7) << 4)));
      }
      #pragma unroll
      for (int fm = 0; fm < 2; ++fm)
        #pragma unroll
        for (int fn = 0; fn < 2; ++fn)
          acc[fm][fn] = __builtin_amdgcn_mfma_f32_16x16x32_bf16(a[fm], b[fn], acc[fm][fn], 0, 0, 0);
    }
  };

  stage(it0, 0);
  stage(it0 + 1, 1);
  asm volatile("s_waitcnt vmcnt(4)" ::: "memory");
  __builtin_amdgcn_s_barrier();
  int cur = 0;
  for (int i = 0; i < nit; ++i) {
    compute(cur);
    __builtin_amdgcn_s_barrier();                 // all waves done reading buf cur
    if (i + 2 < nit) stage(it0 + i + 2, cur);     // overwrite buf cur
    if (i + 1 < nit) {
      if (i + 2 < nit) asm volatile("s_waitcnt vmcnt(4)" ::: "memory");
      else             asm volatile("s_waitcnt vmcnt(0)" ::: "memory");
      __builtin_amdgcn_s_barrier();               // buf cur^1 ready
    }
    cur ^= 1;
  }

  #pragma unroll
  for (int fm = 0; fm < 2; ++fm) {
    int rbase = bm + wr * 32 + fm * 16 + (lane >> 4) * 4;
    #pragma unroll
    for (int fn = 0; fn < 2; ++fn) {
      int col = bn + wc * 32 + fn * 16 + (lane & 15);
      if (col >= ga.N) continue;
      float bv = ga.bias ? ga.bias[col] : 0.0f;
      #pragma unroll
      for (int j = 0; j < 4; ++j) {
        float v = acc[fm][fn][j] + bv;
        if (ga.act == 1) v = fmaxf(v, 0.0f);
        size_t off = (size_t)(rbase + j) * ga.ldc + col;
        if (ga.C) C[off] = v;
        if (ga.C16) ga.C16[off] = __float2bfloat16(v);
      }
    }
  }
}

// ------------------------------------------- 128x128 m97-structure bf16 GEMM
// Template BK: 64 (2 blocks/CU) or 32 (4 blocks/CU, latency-bound fc).
// 2-buffer counted vmcnt, bijective XCD swizzle.
// morder==1: bm-fastest in XCD chunk. cmap==1: row m -> C[(m&127)*ldc+(m>>7)*kV].
struct G128Args {
  const __hip_bfloat16* A; int lda;
  const __hip_bfloat16* WT; int ldk;
  const float* bias;
  float* C; __hip_bfloat16* C16; int ldc; int N; int Ktot; int act; int cmap; int morder;
};

template <int BK>
__global__ __launch_bounds__(256) void gemm128(G128Args ga) {
  constexpr int RB = BK * 2;               // row bytes
  constexpr int TILEB = 128 * RB;          // bytes per matrix tile
  constexpr int ROUNDS = TILEB / 4096;     // staging rounds (4 KB each)
  constexpr int SWZ = (RB == 256) ? 15 : (RB == 128 ? 7 : 3);
  __shared__ char lds[2 * 2 * TILEB];
  const int gx = gridDim.x;
  const int gy = gridDim.y;
  const int nwg = gx * gy;
  int bid = blockIdx.y * gx + blockIdx.x;
  int q = nwg >> 3, r = nwg & 7;
  int xc = bid & 7, yq = bid >> 3;
  int swz = (xc < r ? xc * (q + 1) : r * (q + 1) + (xc - r) * q) + yq;
  int bn, bm;
  if (ga.morder == 1) { bm = (swz % gy) * 128; bn = (swz / gy) * 128; }
  else                { bn = (swz % gx) * 128; bm = (swz / gx) * 128; }

  const int tid = threadIdx.x;
  const int lane = tid & 63;
  const int w = tid >> 6;
  const int wr = w >> 1, wc = w & 1;

  int rowS[ROUNDS], scbS[ROUNDS], dstS[ROUNDS];
  #pragma unroll
  for (int j = 0; j < ROUNDS; ++j) {
    int off = ((j * 4 + w) * 64 + lane) * 16;
    int row = off / RB, colb = off % RB;
    rowS[j] = row;
    scbS[j] = colb ^ ((row & SWZ) << 4);
    dstS[j] = off;
  }

  f32x4 acc[4][4] = {};
  const int nit = ga.Ktot / BK;

  auto stage = [&](int it, int buf) {
    const int k0 = it * BK;
    char* baseA = lds + buf * 2 * TILEB;
    char* baseB = baseA + TILEB;
    #pragma unroll
    for (int j = 0; j < ROUNDS; ++j) {
      const __hip_bfloat16* sA = ga.A + (size_t)(bm + rowS[j]) * ga.lda + k0 + (scbS[j] >> 1);
      __builtin_amdgcn_global_load_lds((AS1C)sA, (AS3P)(baseA + dstS[j]), 16, 0, 0);
      const __hip_bfloat16* sB = ga.WT + (size_t)(bn + rowS[j]) * ga.ldk + k0 + (scbS[j] >> 1);
      __builtin_amdgcn_global_load_lds((AS1C)sB, (AS3P)(baseB + dstS[j]), 16, 0, 0);
    }
  };

  auto compute = [&](int buf) {
    const char* baseA = lds + buf * 2 * TILEB;
    const char* baseB = baseA + TILEB;
    #pragma unroll
    for (int kk = 0; kk < BK / 32; ++kk) {
      bf16x8 a[4], b[4];
      int cb = kk * 64 + (lane >> 4) * 16;
      #pragma unroll
      for (int f = 0; f < 4; ++f) {
        int row = wr * 64 + f * 16 + (lane & 15);
        a[f] = *(const bf16x8*)(baseA + row * RB + (cb ^ ((row & SWZ) << 4)));
        int nl = wc * 64 + f * 16 + (lane & 15);
        b[f] = *(const bf16x8*)(baseB + nl * RB + (cb ^ ((nl & SWZ) << 4)));
      }
      #pragma unroll
      for (int fm = 0; fm < 4; ++fm)
        #pragma unroll
        for (int fn = 0; fn < 4; ++fn)
          acc[fm][fn] = __builtin_amdgcn_mfma_f32_16x16x32_bf16(a[fm], b[fn], acc[fm][fn], 0, 0, 0);
    }
  };

  auto wait_one_stage = [&]() {
    if constexpr (ROUNDS == 4) asm volatile("s_waitcnt vmcnt(8)" ::: "memory");
    else                       asm volatile("s_waitcnt vmcnt(4)" ::: "memory");
  };

  stage(0, 0);
  stage(1, 1);
  wait_one_stage();
  __builtin_amdgcn_s_barrier();
  int cur = 0;
  for (int i = 0; i < nit; ++i) {
    compute(cur);
    __builtin_amdgcn_s_barrier();
    if (i + 2 < nit) stage(i + 2, cur);
    if (i + 1 < nit) {
      if (i + 2 < nit) wait_one_stage();
      else             asm volatile("s_waitcnt vmcnt(0)" ::: "memory");
      __builtin_amdgcn_s_barrier();
    }
    cur ^= 1;
  }

  #pragma unroll
  for (int fm = 0; fm < 4; ++fm) {
    int rbase = bm + wr * 64 + fm * 16 + (lane >> 4) * 4;
    #pragma unroll
    for (int fn = 0; fn < 4; ++fn) {
      int col = bn + wc * 64 + fn * 16 + (lane & 15);
      if (col >= ga.N) continue;
      float bv = ga.bias ? ga.bias[col] : 0.0f;
      #pragma unroll
      for (int j = 0; j < 4; ++j) {
        float v = acc[fm][fn][j] + bv;
        if (ga.act == 1) v = fmaxf(v, 0.0f);
        int m = rbase + j;
        size_t off = ga.cmap == 1
            ? (size_t)(m & 127) * ga.ldc + (size_t)(m >> 7) * kV + col
            : (size_t)m * ga.ldc + col;
        if (ga.C) ga.C[off] = v;
        if (ga.C16) ga.C16[off] = __float2bfloat16(v);
      }
    }
  }
}

// ------------------------------------------------------- small fused kernels
__global__ __launch_bounds__(256) void mean_p(const float* __restrict__ Vfeat,
                                              __hip_bfloat16* __restrict__ meanVb) {
  int idx = blockIdx.x * 256 + threadIdx.x;
  if (idx >= kB * kH) return;
  int b = idx >> 10, h = idx & 1023;
  float sm = 0.0f;
  for (int p = 0; p < kP; ++p) sm += Vfeat[((size_t)b * kP + p) * kH + h];
  meanVb[idx] = __float2bfloat16(sm * (1.0f / kP));
}

// LSTM1 gates + sentinel + full adaptive-attention step. One block per batch.
// g = THREE split-K slabs of [128][5120] raw sums; bias added here.
__global__ __launch_bounds__(256) void step1_fused(
    const float* __restrict__ g, const float* __restrict__ bias_g1,
    float* __restrict__ c1, __hip_bfloat16* __restrict__ h1b,
    const float* __restrict__ img_proj, const float* __restrict__ Vfeat,
    const float* __restrict__ Wg, const float* __restrict__ Ws,
    const float* __restrict__ bs, const float* __restrict__ wh,
    float* __restrict__ c_hat, __hip_bfloat16* __restrict__ c_hatb,
    float* __restrict__ out_alphas, float* __restrict__ out_betas, int t) {
  const int b = blockIdx.x;
  const int tid = threadIdx.x;
  const int lane = tid & 63;
  const int w = tid >> 6;
  __shared__ float sh_h1[kH];
  __shared__ float sh_st[kH];
  __shared__ float wsum[4][36];
  __shared__ float htp[36];
  __shared__ float stp[36];
  __shared__ float alpha[kP];
  __shared__ float sred[4];  // 0: att_vs, 1: beta, 2: zmax, 3: zsum

  const float* gr0 = g + (size_t)b * 5120;
  const float* gr1 = gr0 + kSlab1;
  const float* gr2 = gr1 + kSlab1;
  #pragma unroll
  for (int i = 0; i < 4; ++i) {
    int h = tid + i * 256;
    float pi = gr0[h]           + gr1[h]           + gr2[h]           + bias_g1[h];
    float pf = gr0[kH + h]      + gr1[kH + h]      + gr2[kH + h]      + bias_g1[kH + h];
    float pg = gr0[2 * kH + h]  + gr1[2 * kH + h]  + gr2[2 * kH + h]  + bias_g1[2 * kH + h];
    float po = gr0[3 * kH + h]  + gr1[3 * kH + h]  + gr2[3 * kH + h]  + bias_g1[3 * kH + h];
    float ps = gr0[4 * kH + h]  + gr1[4 * kH + h]  + gr2[4 * kH + h]  + bias_g1[4 * kH + h];
    int idx = b * kH + h;
    float c = sigf(pf) * c1[idx] + sigf(pi) * tanhf(pg);
    float tc = tanhf(c);
    float hn = sigf(po) * tc;
    c1[idx] = c;
    h1b[idx] = __float2bfloat16(hn);
    sh_h1[h] = hn;
    sh_st[h] = sigf(ps) * tc;
  }
  __syncthreads();

  #pragma unroll
  for (int pass = 0; pass < 2; ++pass) {
    const float* vec = pass == 0 ? sh_h1 : sh_st;
    const float* W = pass == 0 ? Wg : Ws;
    float pg[36];
    #pragma unroll
    for (int j = 0; j < 36; ++j) pg[j] = 0.0f;
    #pragma unroll
    for (int i = 0; i < 4; ++i) {
      int hh = tid + i * 256;
      float hv = vec[hh];
      const float4* wrow = reinterpret_cast<const float4*>(W + (size_t)hh * 36);
      #pragma unroll
      for (int r = 0; r < 9; ++r) {
        float4 wv = wrow[r];
        pg[4 * r + 0] = fmaf(hv, wv.x, pg[4 * r + 0]);
        pg[4 * r + 1] = fmaf(hv, wv.y, pg[4 * r + 1]);
        pg[4 * r + 2] = fmaf(hv, wv.z, pg[4 * r + 2]);
        pg[4 * r + 3] = fmaf(hv, wv.w, pg[4 * r + 3]);
      }
    }
    #pragma unroll
    for (int j = 0; j < 36; ++j) {
      float v = pg[j];
      #pragma unroll
      for (int off = 32; off > 0; off >>= 1) v += __shfl_down(v, off, 64);
      if (lane == 0) wsum[w][j] = v;
    }
    __syncthreads();
    if (tid < 36) {
      float s = wsum[0][tid] + wsum[1][tid] + wsum[2][tid] + wsum[3][tid];
      if (pass == 0) htp[tid] = s; else stp[tid] = s;
    }
    __syncthreads();
  }

  if (w == 0) {
    float zz_r = -3.0e38f;
    if (lane < kP) {
      const float* ip = img_proj + ((size_t)b * kP + lane) * kP;
      float acc = 0.0f;
      #pragma unroll
      for (int j = 0; j < kP; ++j) acc = fmaf(tanhf(ip[j] + htp[j]), wh[j], acc);
      zz_r = acc;
    }
    float m = zz_r;
    #pragma unroll
    for (int off = 32; off > 0; off >>= 1) m = fmaxf(m, __shfl_xor(m, off, 64));
    float e = (lane < kP) ? expf(zz_r - m) : 0.0f;
    float s = e;
    #pragma unroll
    for (int off = 32; off > 0; off >>= 1) s += __shfl_xor(s, off, 64);
    if (lane < kP) alpha[lane] = e / s;
    if (lane == 0) { sred[2] = m; sred[3] = s; }
  } else if (w == 1) {
    float tv = 0.0f;
    if (lane < kP) tv = tanhf(stp[lane] + bs[lane] + htp[lane]) * wh[lane];
    #pragma unroll
    for (int off = 32; off > 0; off >>= 1) tv += __shfl_xor(tv, off, 64);
    if (lane == 0) sred[0] = tv;
  }
  __syncthreads();
  if (tid == 0) {
    float av = sred[0], m = sred[2], s = sred[3];
    float m2 = fmaxf(m, av);
    float eb = expf(av - m2);
    float beta = eb / (s * expf(m - m2) + eb);
    sred[1] = beta;
    out_betas[b * kT + t] = beta;
  }
  __syncthreads();
  if (tid < kP) out_alphas[((size_t)b * kT + t) * kP + tid] = alpha[tid];
  const float beta = sred[1];
  #pragma unroll
  for (int i = 0; i < 4; ++i) {
    int h = tid + i * 256;
    float ctx = 0.0f;
    for (int p = 0; p < kP; ++p) ctx = fmaf(alpha[p], Vfeat[((size_t)b * kP + p) * kH + h], ctx);
    float v = beta * sh_st[h] + (1.0f - beta) * ctx;
    c_hat[(size_t)b * kH + h] = v;
    c_hatb[(size_t)b * kH + h] = __float2bfloat16(v);
  }
}

// g: three split-K slabs of [128][4096] raw sums; bias added here.
__global__ __launch_bounds__(256) void lstm2_elem(const float* __restrict__ g,
                                                  const float* __restrict__ bias_g2,
                                                  float* __restrict__ c2,
                                                  __hip_bfloat16* __restrict__ h2b,
                                                  const float* __restrict__ c_hat,
                                                  __hip_bfloat16* __restrict__ sbufb) {
  int idx = blockIdx.x * 256 + threadIdx.x;
  if (idx >= kB * kH) return;
  int b = idx >> 10, h = idx & 1023;
  const float* gr0 = g + (size_t)b * 4 * kH;
  const float* gr1 = gr0 + kSlab2;
  const float* gr2 = gr1 + kSlab2;
  float pi = gr0[h]           + gr1[h]           + gr2[h]           + bias_g2[h];
  float pf = gr0[kH + h]      + gr1[kH + h]      + gr2[kH + h]      + bias_g2[kH + h];
  float pg = gr0[2 * kH + h]  + gr1[2 * kH + h]  + gr2[2 * kH + h]  + bias_g2[2 * kH + h];
  float po = gr0[3 * kH + h]  + gr1[3 * kH + h]  + gr2[3 * kH + h]  + bias_g2[3 * kH + h];
  float c = sigf(pf) * c2[idx] + sigf(pi) * tanhf(pg);
  float hn = sigf(po) * tanhf(c);
  c2[idx] = c;
  h2b[idx] = __float2bfloat16(hn);
  sbufb[idx] = __float2bfloat16(c_hat[idx] + hn);
}

// ------------------------------------------------------------------ launch
extern "C" void kernel_launch(void* const* d_in, const int* in_sizes, int n_in,
                              void* d_out, int out_size, void* d_ws, size_t ws_size,
                              hipStream_t stream) {
  const float* images  = (const float*)d_in[0];
  const int*   caps    = (const int*)d_in[1];
  const float* W_img   = (const float*)d_in[3];
  const float* b_img   = (const float*)d_in[4];
  const float* W_glob  = (const float*)d_in[5];
  const float* b_glob  = (const float*)d_in[6];
  const float* W_ih1   = (const float*)d_in[7];
  const float* W_hh1   = (const float*)d_in[8];
  const float* b_ih1   = (const float*)d_in[9];
  const float* b_hh1   = (const float*)d_in[10];
  const float* Wx_gate = (const float*)d_in[11];
  const float* bx_gate = (const float*)d_in[12];
  const float* Wh_gate = (const float*)d_in[13];
  const float* bh_gate = (const float*)d_in[14];
  const float* W_ih2   = (const float*)d_in[15];
  const float* W_hh2   = (const float*)d_in[16];
  const float* b_ih2   = (const float*)d_in[17];
  const float* b_hh2   = (const float*)d_in[18];
  const float* Wv      = (const float*)d_in[19];
  const float* bv      = (const float*)d_in[20];
  const float* Ws_     = (const float*)d_in[21];
  const float* bs_     = (const float*)d_in[22];
  const float* Wg      = (const float*)d_in[23];
  const float* wh      = (const float*)d_in[24];
  const float* emb     = (const float*)d_in[25];
  const float* W_fc    = (const float*)d_in[26];
  const float* b_fc    = (const float*)d_in[27];

  float* out = (float*)d_out;
  float* out_alphas = out + (size_t)kB * kT * kV;
  float* out_betas  = out_alphas + (size_t)kB * kT * kP;

  char* base = (char*)d_ws;
  auto alloc = [&](size_t bytes) {
    char* p = base;
    base += (bytes + 255) & ~(size_t)255;
    return p;
  };
  float*          Vfeat   = (float*)alloc((size_t)kB * kP * kH * 4);
  __hip_bfloat16* Vfeatb  = (__hip_bfloat16*)alloc((size_t)kB * kP * kH * 2);
  __hip_bfloat16* imagesb = (__hip_bfloat16*)alloc((size_t)kB * kP * kRaw * 2);
  __hip_bfloat16* WTg1    = (__hip_bfloat16*)alloc((size_t)5120 * 3072 * 2);
  __hip_bfloat16* WTg2    = (__hip_bfloat16*)alloc((size_t)4096 * 3072 * 2);
  __hip_bfloat16* WTfc    = (__hip_bfloat16*)alloc((size_t)12032 * 1024 * 2);
  __hip_bfloat16* WTimg   = (__hip_bfloat16*)alloc((size_t)1024 * 2048 * 2);
  __hip_bfloat16* WTglob  = (__hip_bfloat16*)alloc((size_t)512 * 1024 * 2);
  __hip_bfloat16* WTv     = (__hip_bfloat16*)alloc((size_t)64 * 1024 * 2);
  __hip_bfloat16* wembb   = (__hip_bfloat16*)alloc((size_t)kB * kT * kE * 2);
  float*          img_proj= (float*)alloc((size_t)kB * kP * kP * 4);
  __hip_bfloat16* globb   = (__hip_bfloat16*)alloc((size_t)kB * kE * 2);
  __hip_bfloat16* meanVb  = (__hip_bfloat16*)alloc((size_t)kB * kH * 2);
  float*          c1      = (float*)alloc((size_t)2 * kB * kH * 4);  // c1, c2
  float*          c2      = c1 + kB * kH;
  __hip_bfloat16* h1b     = (__hip_bfloat16*)alloc((size_t)2 * kB * kH * 2);
  __hip_bfloat16* h2b     = h1b + kB * kH;
  float*          g1out   = (float*)alloc((size_t)3 * kB * 5120 * 4);  // 3 slabs
  float*          chat    = (float*)alloc((size_t)kB * kH * 4);
  __hip_bfloat16* chatb   = (__hip_bfloat16*)alloc((size_t)kB * kH * 2);
  __hip_bfloat16* sbufall = (__hip_bfloat16*)alloc((size_t)kT * kB * kH * 2);  // [t][b][h]
  float*          bias_g1 = (float*)alloc(5120 * 4);
  float*          bias_g2 = (float*)alloc(4096 * 4);

  // ---- merged prep (1 launch)
  {
    long total = (long)NZ1 + NZ2 + NCV + NPV + NPF + NPB + NGE;
    int blocks = (int)((total + 255) / 256);
    prep_small<<<blocks, 256, 0, stream>>>(
        c1, (uint4*)h1b, images, imagesb, (uint4*)WTv,
        (uint4*)(WTfc + (size_t)12000 * 1024),
        b_ih1, b_hh1, bx_gate, bh_gate, b_ih2, b_hh2, bias_g1, bias_g2,
        caps, emb, wembb);
  }
  // ---- merged transposes (1 launch)
  {
    TAll ta = {};
    int off = 0, j = 0;
    auto add = [&](const float* src, int ldsrc, int K, int N, __hip_bfloat16* dst,
                   int lddst, int koff, int noff) {
      int nbx = (N + 31) / 32, nby = (K + 31) / 32;
      ta.job[j] = {src, dst, ldsrc, K, N, lddst, koff, noff, off, nbx};
      off += nbx * nby;
      ++j;
    };
    add(W_img,   kH,     kRaw, kH,     WTimg,  kRaw, 0, 0);
    add(W_glob,  kE,     kH,   kE,     WTglob, kH,   0, 0);
    add(Wv,      kP,     kH,   kP,     WTv,    kH,   0, 0);
    add(W_ih1,   4 * kH, 2048, 4 * kH, WTg1,   3072, 0, 0);
    add(W_hh1,   4 * kH, 1024, 4 * kH, WTg1,   3072, 2048, 0);
    add(Wx_gate, kH,     2048, kH,     WTg1,   3072, 0, 4096);
    add(Wh_gate, kH,     1024, kH,     WTg1,   3072, 2048, 4096);
    add(W_ih2,   4 * kH, 2048, 4 * kH, WTg2,   3072, 0, 0);
    add(W_hh2,   4 * kH, 1024, 4 * kH, WTg2,   3072, 2048, 0);
    add(W_fc,    kV,     kH,   kV,     WTfc,   kH,   0, 0);
    ta.njobs = j;
    ta.total_blocks = off;
    transpose_all<<<off, 256, 0, stream>>>(ta);
  }

  // Vfeat = relu(images @ W_img + b_img)   [4608 x 1024], K=2048  (BK=64)
  {
    G128Args ga = {};
    ga.A = imagesb; ga.lda = kRaw; ga.WT = WTimg; ga.ldk = kRaw; ga.bias = b_img;
    ga.C = Vfeat; ga.C16 = Vfeatb; ga.ldc = kH; ga.N = kH; ga.Ktot = kRaw;
    ga.act = 1; ga.cmap = 0; ga.morder = 0;
    gemm128<64><<<dim3(kH / 128, kB * kP / 128), 256, 0, stream>>>(ga);
  }
  mean_p<<<(kB * kH + 255) / 256, 256, 0, stream>>>(Vfeat, meanVb);
  // glob = relu(meanV @ W_glob + b_glob)
  {
    GemmBArgs ga = {};
    ga.seg[0] = {meanVb, kH, 0, kH};
    ga.nseg = 1; ga.WT = WTglob; ga.ldk = kH; ga.bias = b_glob;
    ga.C = nullptr; ga.C16 = globb; ga.ldc = kE; ga.N = kE; ga.Ktot = kH; ga.act = 1;
    gemm_bf16<<<dim3(kE / 64, kB / 64, 1), 256, 0, stream>>>(ga);
  }
  // img_proj = Vfeat @ Wv + bv
  {
    GemmBArgs ga = {};
    ga.seg[0] = {Vfeatb, kH, 0, kH};
    ga.nseg = 1; ga.WT = WTv; ga.ldk = kH; ga.bias = bv;
    ga.C = img_proj; ga.C16 = nullptr; ga.ldc = kP; ga.N = kP; ga.Ktot = kH; ga.act = 0;
    gemm_bf16<<<dim3(1, kB * kP / 64, 1), 256, 0, stream>>>(ga);
  }

  // ---- 20 decode steps (4 kernels each; fc deferred)
  for (int t = 0; t < kT; ++t) {
    {  // g1 + sentinel: [128 x 5120], K = 3072, split-K=3 (16 iters @ BK=64)
      GemmBArgs ga = {};
      ga.seg[0] = {h2b, kH, 0, kH};
      ga.seg[1] = {globb, kE, kH, kH + kE};
      ga.seg[2] = {wembb + (size_t)t * kE, kT * kE, kH + kE, 2048};
      ga.seg[3] = {h1b, kH, 2048, 3072};
      ga.nseg = 4; ga.WT = WTg1; ga.ldk = 3072; ga.bias = nullptr;
      ga.C = g1out; ga.C16 = nullptr; ga.ldc = 5120; ga.N = 5120; ga.Ktot = 3072;
      ga.act = 0; ga.zstride = kSlab1;
      gemm_bf16<<<dim3(5120 / 64, kB / 64, 3), 256, 0, stream>>>(ga);
    }
    step1_fused<<<kB, 256, 0, stream>>>(g1out, bias_g1, c1, h1b, img_proj, Vfeat,
                                        Wg, Ws_, bs_, wh, chat, chatb,
                                        out_alphas, out_betas, t);
    {  // g2: [128 x 4096], K = 3072, split-K=3 (16 iters @ BK=64)
      GemmBArgs ga = {};
      ga.seg[0] = {chatb, kH, 0, kH};
      ga.seg[1] = {h1b, kH, kH, 2048};
      ga.seg[2] = {h2b, kH, 2048, 3072};
      ga.nseg = 3; ga.WT = WTg2; ga.ldk = 3072; ga.bias = nullptr;
      ga.C = g1out; ga.C16 = nullptr; ga.ldc = 4096; ga.N = 4096; ga.Ktot = 3072;
      ga.act = 0; ga.zstride = kSlab2;
      gemm_bf16<<<dim3(4096 / 64, kB / 64, 3), 256, 0, stream>>>(ga);
    }
    lstm2_elem<<<(kB * kH + 255) / 256, 256, 0, stream>>>(
        g1out, bias_g2, c2, h2b, chat, sbufall + (size_t)t * kB * kH);
  }

  // ---- batched fc over all steps: [2560 x 12000], K = 1024  (BK=32, 4 blk/CU)
  {
    G128Args ga = {};
    ga.A = sbufall; ga.lda = kH; ga.WT = WTfc; ga.ldk = kH; ga.bias = b_fc;
    ga.C = out; ga.C16 = nullptr; ga.ldc = kT * kV; ga.N = kV; ga.Ktot = kH;
    ga.act = 0; ga.cmap = 1; ga.morder = 1;
    gemm128<32><<<dim3(12032 / 128, kT * kB / 128), 256, 0, stream>>>(ga);
  }
}

// Round 15
// 1522.917 us; speedup vs baseline: 1.0330x; 1.0330x over previous
//
#include <hip/hip_runtime.h>
#include <hip/hip_bf16.h>
#include <math.h>

typedef __attribute__((ext_vector_type(4))) float f32x4;
typedef __attribute__((ext_vector_type(8))) short bf16x8;

constexpr int kB = 128, kT = 20, kH = 1024, kE = 512, kP = 36, kRaw = 2048, kV = 12000;
constexpr int kSlab1 = kB * 5120;
constexpr int kSlab2 = kB * 4096;

__device__ __forceinline__ float sigf(float x) { return 1.0f / (1.0f + expf(-x)); }

#define AS1C const __attribute__((address_space(1))) void*
#define AS3P __attribute__((address_space(3))) void*

// ---------------------------------------------------------------- merged prep
constexpr int NZ1 = 2 * kB * kH / 4;        // float4 zeros over c1,c2
constexpr int NZ2 = 2 * kB * kH * 2 / 16;   // uint4 zeros over h1b,h2b
constexpr int NCV = kB * kP * kRaw / 4;     // images -> bf16 (4 per thread)
constexpr int NPV = 64 * 1024 * 2 / 16;     // WTv zero (uint4)
constexpr int NPF = 32 * 1024 * 2 / 16;     // WTfc pad zero (uint4)
constexpr int NPB = 5120;                   // pack biases
constexpr int NGE = kB * kT * kE;           // gather embeddings

__global__ __launch_bounds__(256) void prep_small(
    float* c1z, uint4* h1z, const float* images, __hip_bfloat16* imagesb,
    uint4* wtv, uint4* wtfc_pad,
    const float* b_ih1, const float* b_hh1, const float* bx, const float* bh,
    const float* b_ih2, const float* b_hh2, float* bias_g1, float* bias_g2,
    const int* caps, const float* emb, __hip_bfloat16* wembb) {
  long idx = (long)blockIdx.x * 256 + threadIdx.x;
  if (idx < NZ1) { reinterpret_cast<float4*>(c1z)[idx] = make_float4(0, 0, 0, 0); return; }
  idx -= NZ1;
  if (idx < NZ2) { h1z[idx] = make_uint4(0, 0, 0, 0); return; }
  idx -= NZ2;
  if (idx < NCV) {
    float4 v = reinterpret_cast<const float4*>(images)[idx];
    __hip_bfloat16* d = imagesb + idx * 4;
    d[0] = __float2bfloat16(v.x); d[1] = __float2bfloat16(v.y);
    d[2] = __float2bfloat16(v.z); d[3] = __float2bfloat16(v.w);
    return;
  }
  idx -= NCV;
  if (idx < NPV) { wtv[idx] = make_uint4(0, 0, 0, 0); return; }
  idx -= NPV;
  if (idx < NPF) { wtfc_pad[idx] = make_uint4(0, 0, 0, 0); return; }
  idx -= NPF;
  if (idx < NPB) {
    int i = (int)idx;
    if (i < 4096) {
      bias_g1[i] = b_ih1[i] + b_hh1[i];
      bias_g2[i] = b_ih2[i] + b_hh2[i];
    } else {
      bias_g1[i] = bx[i - 4096] + bh[i - 4096];
    }
    return;
  }
  idx -= NPB;
  if (idx < NGE) {
    int e = (int)(idx % kE);
    int bt = (int)(idx / kE);
    int t = bt % kT;
    int b = bt / kT;
    int tok = caps[b * (kT + 1) + t];
    wembb[idx] = __float2bfloat16(emb[(size_t)tok * kE + e]);
  }
}

// ------------------------------------------------ merged weight transposes
struct TJob {
  const float* src; __hip_bfloat16* dst;
  int ld_src, K, N, lddst, koff, noff, blk_off, nbx;
};
struct TAll { TJob job[12]; int njobs; int total_blocks; };

__global__ __launch_bounds__(256) void transpose_all(TAll ta) {
  __shared__ float t[32][33];
  int bid = blockIdx.x;
  int ji = 0;
  while (ji + 1 < ta.njobs && bid >= ta.job[ji + 1].blk_off) ++ji;
  const TJob& J = ta.job[ji];
  int lbid = bid - J.blk_off;
  int n0 = (lbid % J.nbx) * 32, k0 = (lbid / J.nbx) * 32;
  int tx = threadIdx.x & 31, ty = threadIdx.x >> 5;  // 32 x 8
  #pragma unroll
  for (int i = 0; i < 32; i += 8) {
    int k = k0 + ty + i, n = n0 + tx;
    t[ty + i][tx] = (k < J.K && n < J.N) ? J.src[(size_t)k * J.ld_src + n] : 0.0f;
  }
  __syncthreads();
  #pragma unroll
  for (int i = 0; i < 32; i += 8) {
    int n = n0 + ty + i, k = k0 + tx;
    if (n < J.N && k < J.K)
      J.dst[(size_t)(n + J.noff) * J.lddst + k + J.koff] = __float2bfloat16(t[tx][ty + i]);
  }
}

// ------------------------------------------------------- 64x64 bf16 MFMA GEMM
// BK=128, 2-buffer counted-vmcnt pipeline. Split-K via gridDim.z.
struct SegB { const __hip_bfloat16* A; int lda; int kstart; int kend; };
struct GemmBArgs {
  SegB seg[4]; int nseg;
  const __hip_bfloat16* WT; int ldk;
  const float* bias;
  float* C; __hip_bfloat16* C16; int ldc; int N; int Ktot; int act; int zstride;
};

__global__ __launch_bounds__(256) void gemm_bf16(GemmBArgs ga) {
  __shared__ char lds[65536];  // 2 bufs x (A 16K | B 16K)
  const int bm = blockIdx.y * 64;
  const int bn = blockIdx.x * 64;
  const int tid = threadIdx.x;
  const int lane = tid & 63;
  const int w = tid >> 6;
  const int wr = w >> 1, wc = w & 1;

  int rowS[4], scbS[4], dstS[4];
  #pragma unroll
  for (int j = 0; j < 4; ++j) {
    int off = ((j * 4 + w) * 64 + lane) * 16;   // linear byte in 16 KB tile
    int row = off >> 8, colb = off & 255;       // 256 B rows (BK=128)
    rowS[j] = row;
    scbS[j] = colb ^ ((row & 7) << 4);
    dstS[j] = (j * 4 + w) * 1024;
  }

  f32x4 acc[2][2] = {};
  const int nz = gridDim.z;
  const int nit = (ga.Ktot >> 7) / nz;
  const int it0 = blockIdx.z * nit;
  float* C = ga.C + (size_t)blockIdx.z * ga.zstride;

  auto stage = [&](int it, int buf) {
    const int k0 = it << 7;
    int si = 0;
    while (k0 >= ga.seg[si].kend) ++si;
    const __hip_bfloat16* Aseg = ga.seg[si].A;
    const int lda = ga.seg[si].lda;
    const int ks = k0 - ga.seg[si].kstart;
    char* baseA = lds + buf * 32768;
    char* baseB = baseA + 16384;
    #pragma unroll
    for (int j = 0; j < 4; ++j) {
      const __hip_bfloat16* sA = Aseg + (size_t)(bm + rowS[j]) * lda + ks + (scbS[j] >> 1);
      __builtin_amdgcn_global_load_lds((AS1C)sA, (AS3P)(baseA + dstS[j]), 16, 0, 0);
      const __hip_bfloat16* sB = ga.WT + (size_t)(bn + rowS[j]) * ga.ldk + k0 + (scbS[j] >> 1);
      __builtin_amdgcn_global_load_lds((AS1C)sB, (AS3P)(baseB + dstS[j]), 16, 0, 0);
    }
  };

  auto compute = [&](int buf) {
    const char* baseA = lds + buf * 32768;
    const char* baseB = baseA + 16384;
    #pragma unroll
    for (int kk = 0; kk < 4; ++kk) {
      bf16x8 a[2], b[2];
      #pragma unroll
      for (int f = 0; f < 2; ++f) {
        int row = wr * 32 + f * 16 + (lane & 15);
        int cb = kk * 64 + (lane >> 4) * 16;
        a[f] = *(const bf16x8*)(baseA + row * 256 + (cb ^ ((row & 7) << 4)));
        int nl = wc * 32 + f * 16 + (lane & 15);
        b[f] = *(const bf16x8*)(baseB + nl * 256 + (cb ^ ((nl & 7) << 4)));
      }
      #pragma unroll
      for (int fm = 0; fm < 2; ++fm)
        #pragma unroll
        for (int fn = 0; fn < 2; ++fn)
          acc[fm][fn] = __builtin_amdgcn_mfma_f32_16x16x32_bf16(a[fm], b[fn], acc[fm][fn], 0, 0, 0);
    }
  };

  stage(it0, 0);
  stage(it0 + 1, 1);
  asm volatile("s_waitcnt vmcnt(8)" ::: "memory");
  __builtin_amdgcn_s_barrier();
  int cur = 0;
  for (int i = 0; i < nit; ++i) {
    compute(cur);
    __builtin_amdgcn_s_barrier();
    if (i + 2 < nit) stage(it0 + i + 2, cur);
    if (i + 1 < nit) {
      if (i + 2 < nit) asm volatile("s_waitcnt vmcnt(8)" ::: "memory");
      else             asm volatile("s_waitcnt vmcnt(0)" ::: "memory");
      __builtin_amdgcn_s_barrier();
    }
    cur ^= 1;
  }

  #pragma unroll
  for (int fm = 0; fm < 2; ++fm) {
    int rbase = bm + wr * 32 + fm * 16 + (lane >> 4) * 4;
    #pragma unroll
    for (int fn = 0; fn < 2; ++fn) {
      int col = bn + wc * 32 + fn * 16 + (lane & 15);
      if (col >= ga.N) continue;
      float bv = ga.bias ? ga.bias[col] : 0.0f;
      #pragma unroll
      for (int j = 0; j < 4; ++j) {
        float v = acc[fm][fn][j] + bv;
        if (ga.act == 1) v = fmaxf(v, 0.0f);
        size_t off = (size_t)(rbase + j) * ga.ldc + col;
        if (ga.C) C[off] = v;
        if (ga.C16) ga.C16[off] = __float2bfloat16(v);
      }
    }
  }
}

// ------------------------------------------- 128x128 m97-structure bf16 GEMM
// Template BK: 64 (2 blocks/CU) or 32 (4 blocks/CU, latency-bound fc).
// 2-buffer counted vmcnt, bijective XCD swizzle.
// morder==1: bm-fastest in XCD chunk. cmap==1: row m -> C[(m&127)*ldc+(m>>7)*kV].
struct G128Args {
  const __hip_bfloat16* A; int lda;
  const __hip_bfloat16* WT; int ldk;
  const float* bias;
  float* C; __hip_bfloat16* C16; int ldc; int N; int Ktot; int act; int cmap; int morder;
};

template <int BK>
__global__ __launch_bounds__(256) void gemm128(G128Args ga) {
  constexpr int RB = BK * 2;               // row bytes
  constexpr int TILEB = 128 * RB;          // bytes per matrix tile
  constexpr int ROUNDS = TILEB / 4096;     // staging rounds (4 KB each)
  constexpr int SWZ = (RB == 256) ? 15 : (RB == 128 ? 7 : 3);
  __shared__ char lds[2 * 2 * TILEB];
  const int gx = gridDim.x;
  const int gy = gridDim.y;
  const int nwg = gx * gy;
  int bid = blockIdx.y * gx + blockIdx.x;
  int q = nwg >> 3, r = nwg & 7;
  int xc = bid & 7, yq = bid >> 3;
  int swz = (xc < r ? xc * (q + 1) : r * (q + 1) + (xc - r) * q) + yq;
  int bn, bm;
  if (ga.morder == 1) { bm = (swz % gy) * 128; bn = (swz / gy) * 128; }
  else                { bn = (swz % gx) * 128; bm = (swz / gx) * 128; }

  const int tid = threadIdx.x;
  const int lane = tid & 63;
  const int w = tid >> 6;
  const int wr = w >> 1, wc = w & 1;

  int rowS[ROUNDS], scbS[ROUNDS], dstS[ROUNDS];
  #pragma unroll
  for (int j = 0; j < ROUNDS; ++j) {
    int off = ((j * 4 + w) * 64 + lane) * 16;
    int row = off / RB, colb = off % RB;
    rowS[j] = row;
    scbS[j] = colb ^ ((row & SWZ) << 4);
    dstS[j] = off;
  }

  f32x4 acc[4][4] = {};
  const int nit = ga.Ktot / BK;

  auto stage = [&](int it, int buf) {
    const int k0 = it * BK;
    char* baseA = lds + buf * 2 * TILEB;
    char* baseB = baseA + TILEB;
    #pragma unroll
    for (int j = 0; j < ROUNDS; ++j) {
      const __hip_bfloat16* sA = ga.A + (size_t)(bm + rowS[j]) * ga.lda + k0 + (scbS[j] >> 1);
      __builtin_amdgcn_global_load_lds((AS1C)sA, (AS3P)(baseA + dstS[j]), 16, 0, 0);
      const __hip_bfloat16* sB = ga.WT + (size_t)(bn + rowS[j]) * ga.ldk + k0 + (scbS[j] >> 1);
      __builtin_amdgcn_global_load_lds((AS1C)sB, (AS3P)(baseB + dstS[j]), 16, 0, 0);
    }
  };

  auto compute = [&](int buf) {
    const char* baseA = lds + buf * 2 * TILEB;
    const char* baseB = baseA + TILEB;
    #pragma unroll
    for (int kk = 0; kk < BK / 32; ++kk) {
      bf16x8 a[4], b[4];
      int cb = kk * 64 + (lane >> 4) * 16;
      #pragma unroll
      for (int f = 0; f < 4; ++f) {
        int row = wr * 64 + f * 16 + (lane & 15);
        a[f] = *(const bf16x8*)(baseA + row * RB + (cb ^ ((row & SWZ) << 4)));
        int nl = wc * 64 + f * 16 + (lane & 15);
        b[f] = *(const bf16x8*)(baseB + nl * RB + (cb ^ ((nl & SWZ) << 4)));
      }
      #pragma unroll
      for (int fm = 0; fm < 4; ++fm)
        #pragma unroll
        for (int fn = 0; fn < 4; ++fn)
          acc[fm][fn] = __builtin_amdgcn_mfma_f32_16x16x32_bf16(a[fm], b[fn], acc[fm][fn], 0, 0, 0);
    }
  };

  auto wait_one_stage = [&]() {
    if constexpr (ROUNDS == 4) asm volatile("s_waitcnt vmcnt(8)" ::: "memory");
    else                       asm volatile("s_waitcnt vmcnt(4)" ::: "memory");
  };

  stage(0, 0);
  stage(1, 1);
  wait_one_stage();
  __builtin_amdgcn_s_barrier();
  int cur = 0;
  for (int i = 0; i < nit; ++i) {
    compute(cur);
    __builtin_amdgcn_s_barrier();
    if (i + 2 < nit) stage(i + 2, cur);
    if (i + 1 < nit) {
      if (i + 2 < nit) wait_one_stage();
      else             asm volatile("s_waitcnt vmcnt(0)" ::: "memory");
      __builtin_amdgcn_s_barrier();
    }
    cur ^= 1;
  }

  #pragma unroll
  for (int fm = 0; fm < 4; ++fm) {
    int rbase = bm + wr * 64 + fm * 16 + (lane >> 4) * 4;
    #pragma unroll
    for (int fn = 0; fn < 4; ++fn) {
      int col = bn + wc * 64 + fn * 16 + (lane & 15);
      if (col >= ga.N) continue;
      float bv = ga.bias ? ga.bias[col] : 0.0f;
      #pragma unroll
      for (int j = 0; j < 4; ++j) {
        float v = acc[fm][fn][j] + bv;
        if (ga.act == 1) v = fmaxf(v, 0.0f);
        int m = rbase + j;
        size_t off = ga.cmap == 1
            ? (size_t)(m & 127) * ga.ldc + (size_t)(m >> 7) * kV + col
            : (size_t)m * ga.ldc + col;
        if (ga.C) ga.C[off] = v;
        if (ga.C16) ga.C16[off] = __float2bfloat16(v);
      }
    }
  }
}

// ------------------------------------------------------- small fused kernels
__global__ __launch_bounds__(256) void mean_p(const float* __restrict__ Vfeat,
                                              __hip_bfloat16* __restrict__ meanVb) {
  int idx = blockIdx.x * 256 + threadIdx.x;
  if (idx >= kB * kH) return;
  int b = idx >> 10, h = idx & 1023;
  float sm = 0.0f;
  for (int p = 0; p < kP; ++p) sm += Vfeat[((size_t)b * kP + p) * kH + h];
  meanVb[idx] = __float2bfloat16(sm * (1.0f / kP));
}

// LSTM1 gates + sentinel + full adaptive-attention step. One block per batch.
// g = THREE split-K slabs of [128][5120] raw sums; bias added here.
__global__ __launch_bounds__(256) void step1_fused(
    const float* __restrict__ g, const float* __restrict__ bias_g1,
    float* __restrict__ c1, __hip_bfloat16* __restrict__ h1b,
    const float* __restrict__ img_proj, const float* __restrict__ Vfeat,
    const float* __restrict__ Wg, const float* __restrict__ Ws,
    const float* __restrict__ bs, const float* __restrict__ wh,
    float* __restrict__ c_hat, __hip_bfloat16* __restrict__ c_hatb,
    float* __restrict__ out_alphas, float* __restrict__ out_betas, int t) {
  const int b = blockIdx.x;
  const int tid = threadIdx.x;
  const int lane = tid & 63;
  const int w = tid >> 6;
  __shared__ float sh_h1[kH];
  __shared__ float sh_st[kH];
  __shared__ float wsum[4][36];
  __shared__ float htp[36];
  __shared__ float stp[36];
  __shared__ float alpha[kP];
  __shared__ float sred[4];  // 0: att_vs, 1: beta, 2: zmax, 3: zsum

  const float* gr0 = g + (size_t)b * 5120;
  const float* gr1 = gr0 + kSlab1;
  const float* gr2 = gr1 + kSlab1;
  #pragma unroll
  for (int i = 0; i < 4; ++i) {
    int h = tid + i * 256;
    float pi = gr0[h]           + gr1[h]           + gr2[h]           + bias_g1[h];
    float pf = gr0[kH + h]      + gr1[kH + h]      + gr2[kH + h]      + bias_g1[kH + h];
    float pg = gr0[2 * kH + h]  + gr1[2 * kH + h]  + gr2[2 * kH + h]  + bias_g1[2 * kH + h];
    float po = gr0[3 * kH + h]  + gr1[3 * kH + h]  + gr2[3 * kH + h]  + bias_g1[3 * kH + h];
    float ps = gr0[4 * kH + h]  + gr1[4 * kH + h]  + gr2[4 * kH + h]  + bias_g1[4 * kH + h];
    int idx = b * kH + h;
    float c = sigf(pf) * c1[idx] + sigf(pi) * tanhf(pg);
    float tc = tanhf(c);
    float hn = sigf(po) * tc;
    c1[idx] = c;
    h1b[idx] = __float2bfloat16(hn);
    sh_h1[h] = hn;
    sh_st[h] = sigf(ps) * tc;
  }
  __syncthreads();

  #pragma unroll
  for (int pass = 0; pass < 2; ++pass) {
    const float* vec = pass == 0 ? sh_h1 : sh_st;
    const float* W = pass == 0 ? Wg : Ws;
    float pg[36];
    #pragma unroll
    for (int j = 0; j < 36; ++j) pg[j] = 0.0f;
    #pragma unroll
    for (int i = 0; i < 4; ++i) {
      int hh = tid + i * 256;
      float hv = vec[hh];
      const float4* wrow = reinterpret_cast<const float4*>(W + (size_t)hh * 36);
      #pragma unroll
      for (int r = 0; r < 9; ++r) {
        float4 wv = wrow[r];
        pg[4 * r + 0] = fmaf(hv, wv.x, pg[4 * r + 0]);
        pg[4 * r + 1] = fmaf(hv, wv.y, pg[4 * r + 1]);
        pg[4 * r + 2] = fmaf(hv, wv.z, pg[4 * r + 2]);
        pg[4 * r + 3] = fmaf(hv, wv.w, pg[4 * r + 3]);
      }
    }
    #pragma unroll
    for (int j = 0; j < 36; ++j) {
      float v = pg[j];
      #pragma unroll
      for (int off = 32; off > 0; off >>= 1) v += __shfl_down(v, off, 64);
      if (lane == 0) wsum[w][j] = v;
    }
    __syncthreads();
    if (tid < 36) {
      float s = wsum[0][tid] + wsum[1][tid] + wsum[2][tid] + wsum[3][tid];
      if (pass == 0) htp[tid] = s; else stp[tid] = s;
    }
    __syncthreads();
  }

  if (w == 0) {
    float zz_r = -3.0e38f;
    if (lane < kP) {
      const float* ip = img_proj + ((size_t)b * kP + lane) * kP;
      float acc = 0.0f;
      #pragma unroll
      for (int j = 0; j < kP; ++j) acc = fmaf(tanhf(ip[j] + htp[j]), wh[j], acc);
      zz_r = acc;
    }
    float m = zz_r;
    #pragma unroll
    for (int off = 32; off > 0; off >>= 1) m = fmaxf(m, __shfl_xor(m, off, 64));
    float e = (lane < kP) ? expf(zz_r - m) : 0.0f;
    float s = e;
    #pragma unroll
    for (int off = 32; off > 0; off >>= 1) s += __shfl_xor(s, off, 64);
    if (lane < kP) alpha[lane] = e / s;
    if (lane == 0) { sred[2] = m; sred[3] = s; }
  } else if (w == 1) {
    float tv = 0.0f;
    if (lane < kP) tv = tanhf(stp[lane] + bs[lane] + htp[lane]) * wh[lane];
    #pragma unroll
    for (int off = 32; off > 0; off >>= 1) tv += __shfl_xor(tv, off, 64);
    if (lane == 0) sred[0] = tv;
  }
  __syncthreads();
  if (tid == 0) {
    float av = sred[0], m = sred[2], s = sred[3];
    float m2 = fmaxf(m, av);
    float eb = expf(av - m2);
    float beta = eb / (s * expf(m - m2) + eb);
    sred[1] = beta;
    out_betas[b * kT + t] = beta;
  }
  __syncthreads();
  if (tid < kP) out_alphas[((size_t)b * kT + t) * kP + tid] = alpha[tid];
  const float beta = sred[1];
  #pragma unroll
  for (int i = 0; i < 4; ++i) {
    int h = tid + i * 256;
    float ctx = 0.0f;
    for (int p = 0; p < kP; ++p) ctx = fmaf(alpha[p], Vfeat[((size_t)b * kP + p) * kH + h], ctx);
    float v = beta * sh_st[h] + (1.0f - beta) * ctx;
    c_hat[(size_t)b * kH + h] = v;
    c_hatb[(size_t)b * kH + h] = __float2bfloat16(v);
  }
}

// g: three split-K slabs of [128][4096] raw sums; bias added here.
__global__ __launch_bounds__(256) void lstm2_elem(const float* __restrict__ g,
                                                  const float* __restrict__ bias_g2,
                                                  float* __restrict__ c2,
                                                  __hip_bfloat16* __restrict__ h2b,
                                                  const float* __restrict__ c_hat,
                                                  __hip_bfloat16* __restrict__ sbufb) {
  int idx = blockIdx.x * 256 + threadIdx.x;
  if (idx >= kB * kH) return;
  int b = idx >> 10, h = idx & 1023;
  const float* gr0 = g + (size_t)b * 4 * kH;
  const float* gr1 = gr0 + kSlab2;
  const float* gr2 = gr1 + kSlab2;
  float pi = gr0[h]           + gr1[h]           + gr2[h]           + bias_g2[h];
  float pf = gr0[kH + h]      + gr1[kH + h]      + gr2[kH + h]      + bias_g2[kH + h];
  float pg = gr0[2 * kH + h]  + gr1[2 * kH + h]  + gr2[2 * kH + h]  + bias_g2[2 * kH + h];
  float po = gr0[3 * kH + h]  + gr1[3 * kH + h]  + gr2[3 * kH + h]  + bias_g2[3 * kH + h];
  float c = sigf(pf) * c2[idx] + sigf(pi) * tanhf(pg);
  float hn = sigf(po) * tanhf(c);
  c2[idx] = c;
  h2b[idx] = __float2bfloat16(hn);
  sbufb[idx] = __float2bfloat16(c_hat[idx] + hn);
}

// ------------------------------------------------------------------ launch
extern "C" void kernel_launch(void* const* d_in, const int* in_sizes, int n_in,
                              void* d_out, int out_size, void* d_ws, size_t ws_size,
                              hipStream_t stream) {
  const float* images  = (const float*)d_in[0];
  const int*   caps    = (const int*)d_in[1];
  const float* W_img   = (const float*)d_in[3];
  const float* b_img   = (const float*)d_in[4];
  const float* W_glob  = (const float*)d_in[5];
  const float* b_glob  = (const float*)d_in[6];
  const float* W_ih1   = (const float*)d_in[7];
  const float* W_hh1   = (const float*)d_in[8];
  const float* b_ih1   = (const float*)d_in[9];
  const float* b_hh1   = (const float*)d_in[10];
  const float* Wx_gate = (const float*)d_in[11];
  const float* bx_gate = (const float*)d_in[12];
  const float* Wh_gate = (const float*)d_in[13];
  const float* bh_gate = (const float*)d_in[14];
  const float* W_ih2   = (const float*)d_in[15];
  const float* W_hh2   = (const float*)d_in[16];
  const float* b_ih2   = (const float*)d_in[17];
  const float* b_hh2   = (const float*)d_in[18];
  const float* Wv      = (const float*)d_in[19];
  const float* bv      = (const float*)d_in[20];
  const float* Ws_     = (const float*)d_in[21];
  const float* bs_     = (const float*)d_in[22];
  const float* Wg      = (const float*)d_in[23];
  const float* wh      = (const float*)d_in[24];
  const float* emb     = (const float*)d_in[25];
  const float* W_fc    = (const float*)d_in[26];
  const float* b_fc    = (const float*)d_in[27];

  float* out = (float*)d_out;
  float* out_alphas = out + (size_t)kB * kT * kV;
  float* out_betas  = out_alphas + (size_t)kB * kT * kP;

  char* base = (char*)d_ws;
  auto alloc = [&](size_t bytes) {
    char* p = base;
    base += (bytes + 255) & ~(size_t)255;
    return p;
  };
  float*          Vfeat   = (float*)alloc((size_t)kB * kP * kH * 4);
  __hip_bfloat16* Vfeatb  = (__hip_bfloat16*)alloc((size_t)kB * kP * kH * 2);
  __hip_bfloat16* imagesb = (__hip_bfloat16*)alloc((size_t)kB * kP * kRaw * 2);
  __hip_bfloat16* WTg1    = (__hip_bfloat16*)alloc((size_t)5120 * 3072 * 2);
  __hip_bfloat16* WTg2    = (__hip_bfloat16*)alloc((size_t)4096 * 3072 * 2);
  __hip_bfloat16* WTfc    = (__hip_bfloat16*)alloc((size_t)12032 * 1024 * 2);
  __hip_bfloat16* WTimg   = (__hip_bfloat16*)alloc((size_t)1024 * 2048 * 2);
  __hip_bfloat16* WTglob  = (__hip_bfloat16*)alloc((size_t)512 * 1024 * 2);
  __hip_bfloat16* WTv     = (__hip_bfloat16*)alloc((size_t)64 * 1024 * 2);
  __hip_bfloat16* wembb   = (__hip_bfloat16*)alloc((size_t)kB * kT * kE * 2);
  float*          img_proj= (float*)alloc((size_t)kB * kP * kP * 4);
  __hip_bfloat16* globb   = (__hip_bfloat16*)alloc((size_t)kB * kE * 2);
  __hip_bfloat16* meanVb  = (__hip_bfloat16*)alloc((size_t)kB * kH * 2);
  float*          c1      = (float*)alloc((size_t)2 * kB * kH * 4);  // c1, c2
  float*          c2      = c1 + kB * kH;
  __hip_bfloat16* h1b     = (__hip_bfloat16*)alloc((size_t)2 * kB * kH * 2);
  __hip_bfloat16* h2b     = h1b + kB * kH;
  float*          g1out   = (float*)alloc((size_t)3 * kB * 5120 * 4);  // 3 slabs
  float*          chat    = (float*)alloc((size_t)kB * kH * 4);
  __hip_bfloat16* chatb   = (__hip_bfloat16*)alloc((size_t)kB * kH * 2);
  __hip_bfloat16* sbufall = (__hip_bfloat16*)alloc((size_t)kT * kB * kH * 2);  // [t][b][h]
  float*          bias_g1 = (float*)alloc(5120 * 4);
  float*          bias_g2 = (float*)alloc(4096 * 4);

  // ---- merged prep (1 launch)
  {
    long total = (long)NZ1 + NZ2 + NCV + NPV + NPF + NPB + NGE;
    int blocks = (int)((total + 255) / 256);
    prep_small<<<blocks, 256, 0, stream>>>(
        c1, (uint4*)h1b, images, imagesb, (uint4*)WTv,
        (uint4*)(WTfc + (size_t)12000 * 1024),
        b_ih1, b_hh1, bx_gate, bh_gate, b_ih2, b_hh2, bias_g1, bias_g2,
        caps, emb, wembb);
  }
  // ---- merged transposes (1 launch)
  {
    TAll ta = {};
    int off = 0, j = 0;
    auto add = [&](const float* src, int ldsrc, int K, int N, __hip_bfloat16* dst,
                   int lddst, int koff, int noff) {
      int nbx = (N + 31) / 32, nby = (K + 31) / 32;
      ta.job[j] = {src, dst, ldsrc, K, N, lddst, koff, noff, off, nbx};
      off += nbx * nby;
      ++j;
    };
    add(W_img,   kH,     kRaw, kH,     WTimg,  kRaw, 0, 0);
    add(W_glob,  kE,     kH,   kE,     WTglob, kH,   0, 0);
    add(Wv,      kP,     kH,   kP,     WTv,    kH,   0, 0);
    add(W_ih1,   4 * kH, 2048, 4 * kH, WTg1,   3072, 0, 0);
    add(W_hh1,   4 * kH, 1024, 4 * kH, WTg1,   3072, 2048, 0);
    add(Wx_gate, kH,     2048, kH,     WTg1,   3072, 0, 4096);
    add(Wh_gate, kH,     1024, kH,     WTg1,   3072, 2048, 4096);
    add(W_ih2,   4 * kH, 2048, 4 * kH, WTg2,   3072, 0, 0);
    add(W_hh2,   4 * kH, 1024, 4 * kH, WTg2,   3072, 2048, 0);
    add(W_fc,    kV,     kH,   kV,     WTfc,   kH,   0, 0);
    ta.njobs = j;
    ta.total_blocks = off;
    transpose_all<<<off, 256, 0, stream>>>(ta);
  }

  // Vfeat = relu(images @ W_img + b_img)   [4608 x 1024], K=2048  (BK=64)
  {
    G128Args ga = {};
    ga.A = imagesb; ga.lda = kRaw; ga.WT = WTimg; ga.ldk = kRaw; ga.bias = b_img;
    ga.C = Vfeat; ga.C16 = Vfeatb; ga.ldc = kH; ga.N = kH; ga.Ktot = kRaw;
    ga.act = 1; ga.cmap = 0; ga.morder = 0;
    gemm128<64><<<dim3(kH / 128, kB * kP / 128), 256, 0, stream>>>(ga);
  }
  mean_p<<<(kB * kH + 255) / 256, 256, 0, stream>>>(Vfeat, meanVb);
  // glob = relu(meanV @ W_glob + b_glob)
  {
    GemmBArgs ga = {};
    ga.seg[0] = {meanVb, kH, 0, kH};
    ga.nseg = 1; ga.WT = WTglob; ga.ldk = kH; ga.bias = b_glob;
    ga.C = nullptr; ga.C16 = globb; ga.ldc = kE; ga.N = kE; ga.Ktot = kH; ga.act = 1;
    gemm_bf16<<<dim3(kE / 64, kB / 64, 1), 256, 0, stream>>>(ga);
  }
  // img_proj = Vfeat @ Wv + bv
  {
    GemmBArgs ga = {};
    ga.seg[0] = {Vfeatb, kH, 0, kH};
    ga.nseg = 1; ga.WT = WTv; ga.ldk = kH; ga.bias = bv;
    ga.C = img_proj; ga.C16 = nullptr; ga.ldc = kP; ga.N = kP; ga.Ktot = kH; ga.act = 0;
    gemm_bf16<<<dim3(1, kB * kP / 64, 1), 256, 0, stream>>>(ga);
  }

  // ---- 20 decode steps (4 kernels each; fc deferred)
  for (int t = 0; t < kT; ++t) {
    {  // g1 + sentinel: [128 x 5120], K = 3072, split-K=3 (8 iters each)
      GemmBArgs ga = {};
      ga.seg[0] = {h2b, kH, 0, kH};
      ga.seg[1] = {globb, kE, kH, kH + kE};
      ga.seg[2] = {wembb + (size_t)t * kE, kT * kE, kH + kE, 2048};
      ga.seg[3] = {h1b, kH, 2048, 3072};
      ga.nseg = 4; ga.WT = WTg1; ga.ldk = 3072; ga.bias = nullptr;
      ga.C = g1out; ga.C16 = nullptr; ga.ldc = 5120; ga.N = 5120; ga.Ktot = 3072;
      ga.act = 0; ga.zstride = kSlab1;
      gemm_bf16<<<dim3(5120 / 64, kB / 64, 3), 256, 0, stream>>>(ga);
    }
    step1_fused<<<kB, 256, 0, stream>>>(g1out, bias_g1, c1, h1b, img_proj, Vfeat,
                                        Wg, Ws_, bs_, wh, chat, chatb,
                                        out_alphas, out_betas, t);
    {  // g2: [128 x 4096], K = 3072, split-K=3 (8 iters each)
      GemmBArgs ga = {};
      ga.seg[0] = {chatb, kH, 0, kH};
      ga.seg[1] = {h1b, kH, kH, 2048};
      ga.seg[2] = {h2b, kH, 2048, 3072};
      ga.nseg = 3; ga.WT = WTg2; ga.ldk = 3072; ga.bias = nullptr;
      ga.C = g1out; ga.C16 = nullptr; ga.ldc = 4096; ga.N = 4096; ga.Ktot = 3072;
      ga.act = 0; ga.zstride = kSlab2;
      gemm_bf16<<<dim3(4096 / 64, kB / 64, 3), 256, 0, stream>>>(ga);
    }
    lstm2_elem<<<(kB * kH + 255) / 256, 256, 0, stream>>>(
        g1out, bias_g2, c2, h2b, chat, sbufall + (size_t)t * kB * kH);
  }

  // ---- batched fc over all steps: [2560 x 12000], K = 1024  (BK=32, 4 blk/CU)
  {
    G128Args ga = {};
    ga.A = sbufall; ga.lda = kH; ga.WT = WTfc; ga.ldk = kH; ga.bias = b_fc;
    ga.C = out; ga.C16 = nullptr; ga.ldc = kT * kV; ga.N = kV; ga.Ktot = kH;
    ga.act = 0; ga.cmap = 1; ga.morder = 1;
    gemm128<32><<<dim3(12032 / 128, kT * kB / 128), 256, 0, stream>>>(ga);
  }
}